// Round 3
// baseline (492.133 us; speedup 1.0000x reference)
//
#include <hip/hip_runtime.h>

#define NN 10000
#define NN_P 10048          // padded rows for guard-free GEMM loads
#define NE 320000
#define F  128

// ---------- CSR build ----------
__global__ void count_kernel(const int* __restrict__ dst, int* __restrict__ deg) {
    int e = blockIdx.x * 256 + threadIdx.x;
    if (e < NE) atomicAdd(&deg[dst[e]], 1);
}

__global__ __launch_bounds__(1024) void scan_kernel(const int* __restrict__ deg,
                                                    int* __restrict__ offs,
                                                    int* __restrict__ cursor,
                                                    float* __restrict__ invdeg) {
    __shared__ int s[1024];
    int t = threadIdx.x;
    int lo = t * 10;
    int hi = min(lo + 10, NN);
    int sum = 0;
    for (int i = lo; i < hi; ++i) sum += deg[i];
    s[t] = sum;
    __syncthreads();
    for (int off = 1; off < 1024; off <<= 1) {
        int v = (t >= off) ? s[t - off] : 0;
        __syncthreads();
        s[t] += v;
        __syncthreads();
    }
    int base = s[t] - sum;  // exclusive prefix
    for (int i = lo; i < hi; ++i) {
        int c = deg[i];
        offs[i]   = base;
        cursor[i] = base;
        invdeg[i] = 1.0f / (float)c;
        base += c;
    }
    if (t == 0) offs[NN] = NE;
}

// fill CSR; also pre-resolve csrc[p] = src[e] (saves a separate NE pass)
__global__ void fill_kernel(const int* __restrict__ dst, const int* __restrict__ src,
                            int* __restrict__ cursor, int* __restrict__ csr,
                            int* __restrict__ csrc) {
    int e = blockIdx.x * 256 + threadIdx.x;
    if (e < NE) {
        int p = atomicAdd(&cursor[dst[e]], 1);
        csr[p] = e;
        csrc[p] = src[e];
    }
}

// ---------- generic CSR gather (float4, 4 edge-rows in flight per node) ----------
// Out[n] = scale[n] * sum_{i in [offs[n],offs[n+1])} op(T[idx[i]])
//   RELU op: relu(0.5*(v + T[n]) + bias)     (fused prev-layer edge compute)
//   else   : v
// block = 256 threads = 2 nodes x 4 edge-slots x 32 float4-chunks
template <bool RELU>
__global__ __launch_bounds__(256) void gather(const float4* __restrict__ T,
                                              const int* __restrict__ idx,
                                              const int* __restrict__ offs,
                                              const float4* __restrict__ bias4,
                                              const float* __restrict__ scale,
                                              float4* __restrict__ Out) {
    int t  = threadIdx.x;
    int ns = t >> 7;          // node slot 0..1
    int es = (t >> 5) & 3;    // edge slot 0..3
    int ch = t & 31;          // float4 chunk 0..31
    int n  = blockIdx.x * 2 + ns;
    int a = offs[n], bnd = offs[n + 1];

    float4 zn = make_float4(0.f, 0.f, 0.f, 0.f);
    float4 b4 = make_float4(0.f, 0.f, 0.f, 0.f);
    if (RELU) {
        zn = T[(size_t)n * 32 + ch];
        b4 = bias4[ch];
    }
    float ax = 0.f, ay = 0.f, az = 0.f, aw = 0.f;

    int i = a + es;
    for (; i + 4 < bnd; i += 8) {
        int s0 = idx[i], s1 = idx[i + 4];
        float4 v0 = T[(size_t)s0 * 32 + ch];
        float4 v1 = T[(size_t)s1 * 32 + ch];
        if (RELU) {
            ax += fmaxf(0.5f * (v0.x + zn.x) + b4.x, 0.f) + fmaxf(0.5f * (v1.x + zn.x) + b4.x, 0.f);
            ay += fmaxf(0.5f * (v0.y + zn.y) + b4.y, 0.f) + fmaxf(0.5f * (v1.y + zn.y) + b4.y, 0.f);
            az += fmaxf(0.5f * (v0.z + zn.z) + b4.z, 0.f) + fmaxf(0.5f * (v1.z + zn.z) + b4.z, 0.f);
            aw += fmaxf(0.5f * (v0.w + zn.w) + b4.w, 0.f) + fmaxf(0.5f * (v1.w + zn.w) + b4.w, 0.f);
        } else {
            ax += v0.x + v1.x; ay += v0.y + v1.y;
            az += v0.z + v1.z; aw += v0.w + v1.w;
        }
    }
    for (; i < bnd; i += 4) {
        int s0 = idx[i];
        float4 v0 = T[(size_t)s0 * 32 + ch];
        if (RELU) {
            ax += fmaxf(0.5f * (v0.x + zn.x) + b4.x, 0.f);
            ay += fmaxf(0.5f * (v0.y + zn.y) + b4.y, 0.f);
            az += fmaxf(0.5f * (v0.z + zn.z) + b4.z, 0.f);
            aw += fmaxf(0.5f * (v0.w + zn.w) + b4.w, 0.f);
        } else {
            ax += v0.x; ay += v0.y; az += v0.z; aw += v0.w;
        }
    }

    __shared__ float4 red[8][32];
    red[t >> 5][ch] = make_float4(ax, ay, az, aw);
    __syncthreads();
    if (t < 64) {
        int ns2 = t >> 5, c2 = t & 31;
        float4 r0 = red[ns2 * 4 + 0][c2];
        float4 r1 = red[ns2 * 4 + 1][c2];
        float4 r2 = red[ns2 * 4 + 2][c2];
        float4 r3 = red[ns2 * 4 + 3][c2];
        int n2 = blockIdx.x * 2 + ns2;
        float sc = scale ? scale[n2] : 1.0f;
        float4 r;
        r.x = (r0.x + r1.x + r2.x + r3.x) * sc;
        r.y = (r0.y + r1.y + r2.y + r3.y) * sc;
        r.z = (r0.z + r1.z + r2.z + r3.z) * sc;
        r.w = (r0.w + r1.w + r2.w + r3.w) * sc;
        Out[(size_t)n2 * 32 + c2] = r;
    }
}

// ---------- node-level GEMM: Z[NN x OUT] = X[NN x 128] @ W[OUT x 128]^T ----------
// grid (OUT/64, NN_P/32), block 256; thread = 2 rows x 4 cols
template <int OUT>
__global__ __launch_bounds__(256) void node_gemm(const float* __restrict__ X,
                                                 const float* __restrict__ Wm,
                                                 float* __restrict__ Z) {
    int tx = threadIdx.x & 15, ty = threadIdx.x >> 4;
    int c0 = blockIdx.x * 64 + tx * 4;
    int r0 = blockIdx.y * 32 + ty * 2;
    float acc[2][4] = {};
#pragma unroll 8
    for (int k = 0; k < 128; k += 4) {
        float4 x0 = *reinterpret_cast<const float4*>(&X[(size_t)r0 * F + k]);
        float4 x1 = *reinterpret_cast<const float4*>(&X[(size_t)(r0 + 1) * F + k]);
        float4 w0 = *reinterpret_cast<const float4*>(&Wm[(size_t)(c0 + 0) * F + k]);
        float4 w1 = *reinterpret_cast<const float4*>(&Wm[(size_t)(c0 + 1) * F + k]);
        float4 w2 = *reinterpret_cast<const float4*>(&Wm[(size_t)(c0 + 2) * F + k]);
        float4 w3 = *reinterpret_cast<const float4*>(&Wm[(size_t)(c0 + 3) * F + k]);
        acc[0][0] += x0.x * w0.x + x0.y * w0.y + x0.z * w0.z + x0.w * w0.w;
        acc[0][1] += x0.x * w1.x + x0.y * w1.y + x0.z * w1.z + x0.w * w1.w;
        acc[0][2] += x0.x * w2.x + x0.y * w2.y + x0.z * w2.z + x0.w * w2.w;
        acc[0][3] += x0.x * w3.x + x0.y * w3.y + x0.z * w3.z + x0.w * w3.w;
        acc[1][0] += x1.x * w0.x + x1.y * w0.y + x1.z * w0.z + x1.w * w0.w;
        acc[1][1] += x1.x * w1.x + x1.y * w1.y + x1.z * w1.z + x1.w * w1.w;
        acc[1][2] += x1.x * w2.x + x1.y * w2.y + x1.z * w2.z + x1.w * w2.w;
        acc[1][3] += x1.x * w3.x + x1.y * w3.y + x1.z * w3.z + x1.w * w3.w;
    }
#pragma unroll
    for (int i = 0; i < 2; ++i) {
        if (r0 + i < NN) {
            float4 v = make_float4(acc[i][0], acc[i][1], acc[i][2], acc[i][3]);
            *reinterpret_cast<float4*>(&Z[(size_t)(r0 + i) * OUT + c0]) = v;
        }
    }
}

// ---------- final edge output: out[e] = 0.5*(z5[src]+z5[dst]) + b5 (64 feats) ----------
__global__ __launch_bounds__(256) void edge_out(const float4* __restrict__ z5,
                                                const float4* __restrict__ b5v,
                                                const int* __restrict__ src,
                                                const int* __restrict__ dst,
                                                float4* __restrict__ outp) {
    int t = blockIdx.x * 256 + threadIdx.x;
    int e = t >> 4, ch = t & 15;
    if (e < NE) {
        float4 a = z5[(size_t)src[e] * 16 + ch];
        float4 b = z5[(size_t)dst[e] * 16 + ch];
        float4 c = b5v[ch];
        float4 r;
        r.x = 0.5f * (a.x + b.x) + c.x;
        r.y = 0.5f * (a.y + b.y) + c.y;
        r.z = 0.5f * (a.z + b.z) + c.z;
        r.w = 0.5f * (a.w + b.w) + c.w;
        outp[(size_t)e * 16 + ch] = r;
    }
}

extern "C" void kernel_launch(void* const* d_in, const int* in_sizes, int n_in,
                              void* d_out, int out_size, void* d_ws, size_t ws_size,
                              hipStream_t stream) {
    const float* ef  = (const float*)d_in[0];
    const int*   src = (const int*)d_in[1];
    const int*   dst = (const int*)d_in[2];
    const float* W1 = (const float*)d_in[3];  const float* b1 = (const float*)d_in[4];
    const float* W2 = (const float*)d_in[5];  const float* b2 = (const float*)d_in[6];
    const float* W3 = (const float*)d_in[7];  const float* b3 = (const float*)d_in[8];
    const float* W4 = (const float*)d_in[9];  const float* b4 = (const float*)d_in[10];
    const float* W5 = (const float*)d_in[11]; const float* b5 = (const float*)d_in[12];
    float* out = (float*)d_out;

    char* p = (char*)d_ws;
    auto alloc = [&](size_t bytes) {
        char* r = p;
        p += (bytes + 255) & ~(size_t)255;
        return r;
    };
    int*   deg    = (int*)alloc(NN * 4);
    int*   offs   = (int*)alloc((NN + 1) * 4);
    int*   cursor = (int*)alloc(NN * 4);
    int*   csr    = (int*)alloc((size_t)NE * 4);
    int*   csrc   = (int*)alloc((size_t)NE * 4);
    float* invdeg = (float*)alloc(NN * 4);
    float* nodeA  = (float*)alloc((size_t)NN_P * F * 4);
    float* nodeB  = (float*)alloc((size_t)NN_P * F * 4);
    float* z      = (float*)alloc((size_t)NN_P * F * 4);

    // CSR build
    hipMemsetAsync(deg, 0, NN * 4, stream);
    count_kernel<<<(NE + 255) / 256, 256, 0, stream>>>(dst, deg);
    scan_kernel<<<1, 1024, 0, stream>>>(deg, offs, cursor, invdeg);
    fill_kernel<<<(NE + 255) / 256, 256, 0, stream>>>(dst, src, cursor, csr, csrc);

    dim3 blk(256);
    dim3 grid128(2, NN_P / 32);
    dim3 grid64(1, NN_P / 32);
    int ggather = NN / 2;

    const float4* z4  = (const float4*)z;
    float4* nodeA4 = (float4*)nodeA;
    float4* nodeB4 = (float4*)nodeB;

    // ---- layer 1 ----
    gather<false><<<ggather, blk, 0, stream>>>((const float4*)ef, csr, offs, nullptr, invdeg, nodeA4);
    gather<false><<<ggather, blk, 0, stream>>>((const float4*)nodeA, csrc, offs, nullptr, nullptr, nodeB4);
    node_gemm<128><<<grid128, blk, 0, stream>>>(nodeB, W1, z);

    // ---- layers 2..4: fused prev-layer edge compute in the RELU gather ----
    const float* bprev[3] = {b1, b2, b3};
    const float* Wl[3]    = {W2, W3, W4};
    for (int L = 0; L < 3; ++L) {
        gather<true><<<ggather, blk, 0, stream>>>(z4, csrc, offs, (const float4*)bprev[L], invdeg, nodeA4);
        gather<false><<<ggather, blk, 0, stream>>>((const float4*)nodeA, csrc, offs, nullptr, nullptr, nodeB4);
        node_gemm<128><<<grid128, blk, 0, stream>>>(nodeB, Wl[L], z);
    }

    // ---- layer 5 ----
    gather<true><<<ggather, blk, 0, stream>>>(z4, csrc, offs, (const float4*)b4, invdeg, nodeA4);
    gather<false><<<ggather, blk, 0, stream>>>((const float4*)nodeA, csrc, offs, nullptr, nullptr, nodeB4);
    node_gemm<64><<<grid64, blk, 0, stream>>>(nodeB, W5, z);

    // ---- final per-edge output (82 MB write) ----
    edge_out<<<(NE * 16 + 255) / 256, blk, 0, stream>>>(z4, (const float4*)b5, src, dst, (float4*)out);
}